// Round 16
// baseline (82.068 us; speedup 1.0000x reference)
//
#include <hip/hip_runtime.h>
#include <hip/hip_bf16.h>
#include <cstdint>

#define NN 2048
#define FF 64
#define BCC 16

typedef float f32x4 __attribute__((ext_vector_type(4)));
typedef int   i32x4 __attribute__((ext_vector_type(4)));
typedef _Float16 half8 __attribute__((ext_vector_type(8)));
typedef uint32_t u32x4 __attribute__((ext_vector_type(4)));

// ---------------- workspace layout (bytes) ----------------
// xPh  : fp16 packed [16][jt=64][nb=4][lane=64][e=8] = 4,194,304  (off 0)
// Uh   : f16 [16][2048] = 65,536  (off 4,194,304)   e^{f2}
// Vh   : f16 [16][2048] = 65,536  (off 4,259,840)   e^{0.1 f2}
// CIh  : f16 [16][2048] = 65,536  (off 4,325,376)   e^{-0.9 f1}
// ADJP : u8  [row=2048][g=4][jt=64] = 524,288 (off 4,390,912)
// CNT  : u32 [48] (off 4,915,200)  cnt[0..15]=per-bc, cnt[16..47]=per-iblk
#define CNT_OFF 4915200

union SmemU {
    struct { float tile[32][65]; float red[2][32][8]; } p;           // 10.4 KB
    struct { _Float16 su[2048]; _Float16 sv[2048]; u32x4 lut[256];
             float part[4][16][68]; float zp[4][16]; } m;            // 29.9 KB
};

// Fused kernel: 512 blocks x 256 threads, guaranteed >=2 blocks/CU resident
// (LDS 29.9KB, VGPR<=256) -> all 512 co-resident -> producer flags safe.
// Phase A: block (bc,iblk) packs its own 2 xP jt-tiles + dots for its 64 rows
//          + 4 ADJP rows (rows iblk*64 + bc*4 .. +4).
// Flags:   arrive on cnt_bc[bc] (target 32) and cnt_ib[iblk] (target 16).
// Phase B: R14 k_main body (M=64/wave, fp16 pk weight math, LUT masks).
__global__ __launch_bounds__(256, 2) void k_fused(
        const float* __restrict__ x, const int* __restrict__ adj,
        const float* __restrict__ a1, const float* __restrict__ a2,
        _Float16* __restrict__ xP, _Float16* __restrict__ Uh,
        _Float16* __restrict__ Vh, _Float16* __restrict__ CIh,
        unsigned char* __restrict__ ADJP, unsigned* __restrict__ cnt,
        float* __restrict__ out) {
    __shared__ SmemU sm;
    int tid = threadIdx.x;

    // XCD swizzle: 2 bc per XCD, 32 iblks each
    int xcd = blockIdx.x & 7, kk = blockIdx.x >> 3;   // kk in 0..63
    int bc   = (xcd << 1) | (kk >> 5);
    int iblk = kk & 31;
    int i0   = iblk * 64;

    // ================= Phase A1: 2 x-tiles of OWN bc + dot tables ==========
    #pragma unroll
    for (int tt = 0; tt < 2; tt++) {
        int jt = iblk * 2 + tt;              // this block's jt tiles
        int n0 = jt * 32;
        int row = tid >> 3;                  // 0..31
        int fo  = (tid & 7) * 8;             // f-octet base

        const float* xr = x + ((size_t)bc * NN + n0 + row) * FF + fo;
        f32x4 v0 = *(const f32x4*)xr;
        f32x4 v1 = *(const f32x4*)(xr + 4);
        *(f32x4*)&sm.p.tile[row][fo]     = v0;
        *(f32x4*)&sm.p.tile[row][fo + 4] = v1;

        f32x4 a1v0 = *(const f32x4*)(a1 + fo);
        f32x4 a1v1 = *(const f32x4*)(a1 + fo + 4);
        f32x4 a2v0 = *(const f32x4*)(a2 + fo);
        f32x4 a2v1 = *(const f32x4*)(a2 + fo + 4);
        float d1 = 0.f, d2 = 0.f;
        #pragma unroll
        for (int e = 0; e < 4; e++) {
            d1 += v0[e] * a1v0[e] + v1[e] * a1v1[e];
            d2 += v0[e] * a2v0[e] + v1[e] * a2v1[e];
        }
        sm.p.red[0][row][tid & 7] = d1;
        sm.p.red[1][row][tid & 7] = d2;
        __syncthreads();

        {   // packed fragment-order write (coalesced)
            int nb = tid >> 6, lane = tid & 63;
            int g = lane >> 4, l15 = lane & 15;
            half8 val;
            #pragma unroll
            for (int e = 0; e < 8; e++)
                val[e] = (_Float16)sm.p.tile[8 * g + e][nb * 16 + l15];
            ((half8*)xP)[(((size_t)bc * 64 + jt) * 4 + nb) * 64 + lane] = val;
        }
        if (tid < 32) {
            float f1 = 0.f, f2 = 0.f;
            #pragma unroll
            for (int s = 0; s < 8; s++) { f1 += sm.p.red[0][tid][s]; f2 += sm.p.red[1][tid][s]; }
            int idx = bc * NN + n0 + tid;
            Uh[idx]  = (_Float16)expf(f2);
            Vh[idx]  = (_Float16)expf(0.1f * f2);
            CIh[idx] = (_Float16)expf(-0.9f * f1);
        }
        __syncthreads();   // tile reused / phase transition
    }

    // ================= Phase A2: 4 ADJP rows (unique across grid) ==========
    {
        int wid  = tid >> 6, lane = tid & 63;
        int row  = iblk * 64 + bc * 4 + wid;             // covers all 2048 rows
        const int* ar = adj + (size_t)row * NN;
        unsigned char* ap = ADJP + (size_t)row * 256;
        #pragma unroll
        for (int m = 0; m < 4; m++) {
            int o = lane + 64 * m;            // octet index (j = 8o..8o+7)
            const int* pj = ar + 8 * o;
            i32x4 w0 = *(const i32x4*)pj;
            i32x4 w1 = *(const i32x4*)(pj + 4);
            uint32_t b = 0;
            #pragma unroll
            for (int e = 0; e < 4; e++) {
                b |= (w0[e] > 0 ? 1u : 0u) << e;
                b |= (w1[e] > 0 ? 1u : 0u) << (e + 4);
            }
            ap[(o & 3) * 64 + (o >> 2)] = (unsigned char)b;   // [g][jt]
        }
    }

    // ================= arrive + wait on dependencies =======================
    __syncthreads();
    if (tid == 0) {
        __threadfence();                       // release: publish A's stores
        atomicAdd(&cnt[bc], 1u);               // xP + u/v of bc
        atomicAdd(&cnt[16 + iblk], 1u);        // ADJP rows of iblk
        while (atomicAdd(&cnt[bc], 0u) < 32u)        __builtin_amdgcn_s_sleep(2);
        while (atomicAdd(&cnt[16 + iblk], 0u) < 16u) __builtin_amdgcn_s_sleep(2);
        __threadfence();                       // acquire: invalidate stale
    }
    __syncthreads();

    // ======================= Phase B: main compute =========================
    int jq = tid >> 6, lane = tid & 63;
    int l15 = lane & 15, g = lane >> 4;

    ((u32x4*)sm.m.su)[tid] = ((const u32x4*)(Uh + bc * NN))[tid];
    ((u32x4*)sm.m.sv)[tid] = ((const u32x4*)(Vh + bc * NN))[tid];
    {   // mask LUT: entry b -> 4 u32 AND-masks for fp16 pairs
        uint32_t bb = tid;
        u32x4 lv;
        #pragma unroll
        for (int w = 0; w < 4; w++)
            lv[w] = (((bb >> (2 * w)) & 1u) ? 0xFFFFu : 0u)
                  | (((bb >> (2 * w + 1)) & 1u) ? 0xFFFF0000u : 0u);
        sm.m.lut[bb] = lv;
    }
    const unsigned char* ab = ADJP + g * 64 + jq * 16;
    u32x4 adjw0 = *(const u32x4*)(ab + (size_t)(i0 + l15) * 256);
    u32x4 adjw1 = *(const u32x4*)(ab + (size_t)(i0 + 16 + l15) * 256);
    u32x4 adjw2 = *(const u32x4*)(ab + (size_t)(i0 + 32 + l15) * 256);
    u32x4 adjw3 = *(const u32x4*)(ab + (size_t)(i0 + 48 + l15) * 256);
    _Float16 Ci0 = CIh[bc * NN + i0 + l15];
    _Float16 Ci1 = CIh[bc * NN + i0 + 16 + l15];
    _Float16 Ci2 = CIh[bc * NN + i0 + 32 + l15];
    _Float16 Ci3 = CIh[bc * NN + i0 + 48 + l15];
    __syncthreads();

    f32x4 acc[4][4];
    #pragma unroll
    for (int a = 0; a < 4; a++)
        #pragma unroll
        for (int nb = 0; nb < 4; nb++)
            acc[a][nb] = (f32x4){0.f, 0.f, 0.f, 0.f};
    f32x4 accz[4];
    #pragma unroll
    for (int a = 0; a < 4; a++) accz[a] = (f32x4){0.f, 0.f, 0.f, 0.f};
    half8 onesh;
    #pragma unroll
    for (int e = 0; e < 8; e++) onesh[e] = (_Float16)1.0f;

    const u32x4* xPbc = (const u32x4*)xP + (size_t)bc * 16384;

    u32x4 A_x0, A_x1, A_x2, A_x3, B_x0, B_x1, B_x2, B_x3;

#define LOADX(P, J) do {                                                      \
        const u32x4* xw_ = xPbc + (((size_t)(jq * 16 + (J))) << 8) + lane;    \
        P##x0 = xw_[0]; P##x1 = xw_[64]; P##x2 = xw_[128]; P##x3 = xw_[192];  \
    } while (0)

#define GEN(AF, ADJW, CI) do {                                                \
        uint32_t b_ = (ADJW[(J_) >> 2] >> (((J_) & 3) * 8)) & 0xffu;          \
        u32x4 mm_ = sm.m.lut[b_];                                             \
        half8 mx_ = __builtin_elementwise_max(uu_, vv_ * (CI));               \
        AF = __builtin_bit_cast(half8, __builtin_bit_cast(u32x4, mx_) & mm_); \
    } while (0)

#define COMP(P, J) do {                                                       \
        const int J_ = (J);                                                   \
        const int jo_ = (jq * 16 + J_) * 32 + 8 * g;                          \
        half8 uu_ = *(const half8*)&sm.m.su[jo_];                             \
        half8 vv_ = *(const half8*)&sm.m.sv[jo_];                             \
        half8 af0_, af1_, af2_, af3_;                                         \
        GEN(af0_, adjw0, Ci0); GEN(af1_, adjw1, Ci1);                         \
        GEN(af2_, adjw2, Ci2); GEN(af3_, adjw3, Ci3);                         \
        half8 b0_ = __builtin_bit_cast(half8, P##x0);                         \
        half8 b1_ = __builtin_bit_cast(half8, P##x1);                         \
        half8 b2_ = __builtin_bit_cast(half8, P##x2);                         \
        half8 b3_ = __builtin_bit_cast(half8, P##x3);                         \
        __builtin_amdgcn_s_setprio(1);                                        \
        acc[0][0] = __builtin_amdgcn_mfma_f32_16x16x32_f16(af0_, b0_, acc[0][0], 0, 0, 0); \
        acc[0][1] = __builtin_amdgcn_mfma_f32_16x16x32_f16(af0_, b1_, acc[0][1], 0, 0, 0); \
        acc[0][2] = __builtin_amdgcn_mfma_f32_16x16x32_f16(af0_, b2_, acc[0][2], 0, 0, 0); \
        acc[0][3] = __builtin_amdgcn_mfma_f32_16x16x32_f16(af0_, b3_, acc[0][3], 0, 0, 0); \
        accz[0]   = __builtin_amdgcn_mfma_f32_16x16x32_f16(af0_, onesh, accz[0], 0, 0, 0); \
        acc[1][0] = __builtin_amdgcn_mfma_f32_16x16x32_f16(af1_, b0_, acc[1][0], 0, 0, 0); \
        acc[1][1] = __builtin_amdgcn_mfma_f32_16x16x32_f16(af1_, b1_, acc[1][1], 0, 0, 0); \
        acc[1][2] = __builtin_amdgcn_mfma_f32_16x16x32_f16(af1_, b2_, acc[1][2], 0, 0, 0); \
        acc[1][3] = __builtin_amdgcn_mfma_f32_16x16x32_f16(af1_, b3_, acc[1][3], 0, 0, 0); \
        accz[1]   = __builtin_amdgcn_mfma_f32_16x16x32_f16(af1_, onesh, accz[1], 0, 0, 0); \
        acc[2][0] = __builtin_amdgcn_mfma_f32_16x16x32_f16(af2_, b0_, acc[2][0], 0, 0, 0); \
        acc[2][1] = __builtin_amdgcn_mfma_f32_16x16x32_f16(af2_, b1_, acc[2][1], 0, 0, 0); \
        acc[2][2] = __builtin_amdgcn_mfma_f32_16x16x32_f16(af2_, b2_, acc[2][2], 0, 0, 0); \
        acc[2][3] = __builtin_amdgcn_mfma_f32_16x16x32_f16(af2_, b3_, acc[2][3], 0, 0, 0); \
        accz[2]   = __builtin_amdgcn_mfma_f32_16x16x32_f16(af2_, onesh, accz[2], 0, 0, 0); \
        acc[3][0] = __builtin_amdgcn_mfma_f32_16x16x32_f16(af3_, b0_, acc[3][0], 0, 0, 0); \
        acc[3][1] = __builtin_amdgcn_mfma_f32_16x16x32_f16(af3_, b1_, acc[3][1], 0, 0, 0); \
        acc[3][2] = __builtin_amdgcn_mfma_f32_16x16x32_f16(af3_, b2_, acc[3][2], 0, 0, 0); \
        acc[3][3] = __builtin_amdgcn_mfma_f32_16x16x32_f16(af3_, b3_, acc[3][3], 0, 0, 0); \
        accz[3]   = __builtin_amdgcn_mfma_f32_16x16x32_f16(af3_, onesh, accz[3], 0, 0, 0); \
        __builtin_amdgcn_s_setprio(0);                                        \
    } while (0)

    LOADX(A_, 0);
    LOADX(B_, 1);  COMP(A_, 0);
    LOADX(A_, 2);  COMP(B_, 1);
    LOADX(B_, 3);  COMP(A_, 2);
    LOADX(A_, 4);  COMP(B_, 3);
    LOADX(B_, 5);  COMP(A_, 4);
    LOADX(A_, 6);  COMP(B_, 5);
    LOADX(B_, 7);  COMP(A_, 6);
    LOADX(A_, 8);  COMP(B_, 7);
    LOADX(B_, 9);  COMP(A_, 8);
    LOADX(A_, 10); COMP(B_, 9);
    LOADX(B_, 11); COMP(A_, 10);
    LOADX(A_, 12); COMP(B_, 11);
    LOADX(B_, 13); COMP(A_, 12);
    LOADX(A_, 14); COMP(B_, 13);
    LOADX(B_, 15); COMP(A_, 14);
    COMP(B_, 15);
#undef LOADX
#undef GEN
#undef COMP

    // ---- epilogue: 4 passes (one per a-tile) ----
    float* outp = out + ((size_t)bc * NN + i0) * FF;
    #pragma unroll
    for (int a = 0; a < 4; a++) {
        #pragma unroll
        for (int nb = 0; nb < 4; nb++)
            #pragma unroll
            for (int r = 0; r < 4; r++)
                sm.m.part[jq][4 * g + r][nb * 16 + l15] = acc[a][nb][r];
        if (l15 == 0) {
            #pragma unroll
            for (int r = 0; r < 4; r++)
                sm.m.zp[jq][4 * g + r] = accz[a][r];
        }
        __syncthreads();
        #pragma unroll
        for (int rr = 0; rr < 4; rr++) {
            int row = jq * 4 + rr;
            float s = sm.m.part[0][row][lane] + sm.m.part[1][row][lane]
                    + sm.m.part[2][row][lane] + sm.m.part[3][row][lane];
            float z = sm.m.zp[0][row] + sm.m.zp[1][row]
                    + sm.m.zp[2][row] + sm.m.zp[3][row];
            outp[(size_t)(16 * a + row) * FF + lane] = s / z;
        }
        __syncthreads();
    }
}

extern "C" void kernel_launch(void* const* d_in, const int* in_sizes, int n_in,
                              void* d_out, int out_size, void* d_ws, size_t ws_size,
                              hipStream_t stream) {
    const float* x  = (const float*)d_in[0];
    const int* adj  = (const int*)d_in[1];
    const float* a1 = (const float*)d_in[2];
    const float* a2 = (const float*)d_in[3];
    float* out = (float*)d_out;

    char* ws = (char*)d_ws;
    _Float16* xP  = (_Float16*)ws;
    _Float16* Uh  = (_Float16*)(ws + 4194304);
    _Float16* Vh  = (_Float16*)(ws + 4259840);
    _Float16* CIh = (_Float16*)(ws + 4325376);
    unsigned char* ADJP = (unsigned char*)(ws + 4390912);
    unsigned* cnt = (unsigned*)(ws + CNT_OFF);

    hipMemsetAsync(cnt, 0, 48 * sizeof(unsigned), stream);
    k_fused<<<512, 256, 0, stream>>>(x, adj, a1, a2, xP, Uh, Vh, CIh, ADJP,
                                     cnt, out);
}

// Round 17
// 24.228 us; speedup vs baseline: 3.3873x; 3.3873x over previous
//
#include <hip/hip_runtime.h>
#include <hip/hip_bf16.h>
#include <cstdint>

#define NN 2048
#define FF 64
#define BCC 16

typedef float f32x4 __attribute__((ext_vector_type(4)));
typedef int   i32x4 __attribute__((ext_vector_type(4)));
typedef _Float16 half8 __attribute__((ext_vector_type(8)));
typedef uint32_t u32x4 __attribute__((ext_vector_type(4)));

// ---------------- workspace layout (bytes) ----------------
// xPh  : fp16 packed [16][jt=64][nb=4][lane=64][e=8] = 4,194,304  (off 0)
//        element (bc,jt,nb,(g,l15),e) = x[bc][n = jt*32+8g+e][f = nb*16+l15]
// Uh   : f16 [16][2048] = 65,536  (off 4,194,304)   e^{f2}
// Vh   : f16 [16][2048] = 65,536  (off 4,259,840)   e^{0.1 f2}
// CIh  : f16 [16][2048] = 65,536  (off 4,325,376)   e^{-0.9 f1}
// ADJP : u8  [row=2048][g=4][jt=64] = 524,288 (off 4,390,912)
//        byte (row,g,jt) bits t = adj[row][jt*32+8g+t]
// total ~4.9 MB

// consolidated prep: 512 blocks. XCD-ALIGNED x-pack: block b (xcd = b&7)
// packs tiles of bc = (xcd<<1)|(q>>5) — the SAME bc that k_main blocks on
// this XCD will consume, so the xP panel stays in the local L2.
__global__ __launch_bounds__(256) void k_prep(const float* __restrict__ x,
        const int* __restrict__ adj,
        const float* __restrict__ a1, const float* __restrict__ a2,
        _Float16* __restrict__ xP, _Float16* __restrict__ Uh,
        _Float16* __restrict__ Vh, _Float16* __restrict__ CIh,
        unsigned char* __restrict__ ADJP) {
    __shared__ float tile[32][65];
    __shared__ float red[2][32][8];
    int tid = threadIdx.x;

    // ---- x pack + tables: 2 tiles (32 rows each), XCD-aligned bc ----
    int xcd = blockIdx.x & 7, q = blockIdx.x >> 3;   // q in 0..63
    int bc  = (xcd << 1) | (q >> 5);                 // matches k_main's map
    int pr  = q & 31;                                // tile-pair index 0..31
    #pragma unroll
    for (int tt = 0; tt < 2; tt++) {
        int jt = pr * 2 + tt;                // 0..63
        int n0 = jt * 32;
        int row = tid >> 3;                  // 0..31
        int fo  = (tid & 7) * 8;             // f-octet base

        const float* xr = x + ((size_t)bc * NN + n0 + row) * FF + fo;
        f32x4 v0 = *(const f32x4*)xr;
        f32x4 v1 = *(const f32x4*)(xr + 4);
        *(f32x4*)&tile[row][fo]     = v0;
        *(f32x4*)&tile[row][fo + 4] = v1;

        // dots from registers (no LDS round-trip)
        f32x4 a1v0 = *(const f32x4*)(a1 + fo);
        f32x4 a1v1 = *(const f32x4*)(a1 + fo + 4);
        f32x4 a2v0 = *(const f32x4*)(a2 + fo);
        f32x4 a2v1 = *(const f32x4*)(a2 + fo + 4);
        float d1 = 0.f, d2 = 0.f;
        #pragma unroll
        for (int e = 0; e < 4; e++) {
            d1 += v0[e] * a1v0[e] + v1[e] * a1v1[e];
            d2 += v0[e] * a2v0[e] + v1[e] * a2v1[e];
        }
        red[0][row][tid & 7] = d1;
        red[1][row][tid & 7] = d2;
        __syncthreads();

        // packed fragment-order write: thread = (nb = tid>>6, lane = tid&63)
        {
            int nb = tid >> 6, lane = tid & 63;
            int g = lane >> 4, l15 = lane & 15;
            half8 val;
            #pragma unroll
            for (int e = 0; e < 8; e++)
                val[e] = (_Float16)tile[8 * g + e][nb * 16 + l15];
            ((half8*)xP)[(((size_t)bc * 64 + jt) * 4 + nb) * 64 + lane] = val;
        }
        // finalize dots
        if (tid < 32) {
            float f1 = 0.f, f2 = 0.f;
            #pragma unroll
            for (int s = 0; s < 8; s++) { f1 += red[0][tid][s]; f2 += red[1][tid][s]; }
            int idx = bc * NN + n0 + tid;
            Uh[idx]  = (_Float16)expf(f2);
            Vh[idx]  = (_Float16)expf(0.1f * f2);
            CIh[idx] = (_Float16)expf(-0.9f * f1);
        }
        __syncthreads();   // tile reused next iteration
    }

    // ---- adj -> ADJP: 4 rows per block, one row per wave ----
    {
        int wid  = tid >> 6, lane = tid & 63;
        int row  = blockIdx.x * 4 + wid;                 // 2048 rows
        const int* ar = adj + (size_t)row * NN;
        unsigned char* ap = ADJP + (size_t)row * 256;
        #pragma unroll
        for (int m = 0; m < 4; m++) {
            int o = lane + 64 * m;            // octet index 0..255 (j = 8o..8o+7)
            const int* pj = ar + 8 * o;
            i32x4 w0 = *(const i32x4*)pj;
            i32x4 w1 = *(const i32x4*)(pj + 4);
            uint32_t b = 0;
            #pragma unroll
            for (int e = 0; e < 4; e++) {
                b |= (w0[e] > 0 ? 1u : 0u) << e;
                b |= (w1[e] > 0 ? 1u : 0u) << (e + 4);
            }
            ap[(o & 3) * 64 + (o >> 2)] = (unsigned char)b;   // [g=o&3][jt=o>>2]
        }
    }
}

// main: block = (bc, 64-row i-block); 4 waves, wave jq owns j-quarter (512 j).
// Each wave: M=64 (4 a-tiles) x F=64 (4 nb), fp16 packed weight math:
//   w' = adj * max(u_j, Ci*v_j)   (softmax row-scale invariance)
// via v_pk_mul_f16 + v_pk_max_f16 + LDS-LUT AND, feeding mfma_f32_16x16x32_f16.
__global__ __launch_bounds__(256) void k_main(
        const _Float16* __restrict__ xP, const _Float16* __restrict__ Uh,
        const _Float16* __restrict__ Vh, const _Float16* __restrict__ CIh,
        const unsigned char* __restrict__ ADJP, float* __restrict__ out) {
    __shared__ _Float16 su[2048];
    __shared__ _Float16 sv[2048];
    __shared__ u32x4 lut[256];
    __shared__ float part[4][16][68];
    __shared__ float zp[4][16];

    int tid = threadIdx.x;
    int jq = tid >> 6, lane = tid & 63;
    int l15 = lane & 15, g = lane >> 4;

    // XCD swizzle: 2 bc per XCD, 32 iblks each
    int xcd = blockIdx.x & 7, kk = blockIdx.x >> 3;   // kk in 0..63
    int bc   = (xcd << 1) | (kk >> 5);
    int iblk = kk & 31;
    int i0   = iblk * 64;

    // stage u/v into LDS (4 KB each; 256 threads x 16 B)
    ((u32x4*)su)[tid] = ((const u32x4*)(Uh + bc * NN))[tid];
    ((u32x4*)sv)[tid] = ((const u32x4*)(Vh + bc * NN))[tid];
    {   // mask LUT: entry b -> 4 u32 AND-masks for fp16 pairs
        uint32_t bb = tid;
        u32x4 lv;
        #pragma unroll
        for (int w = 0; w < 4; w++)
            lv[w] = (((bb >> (2 * w)) & 1u) ? 0xFFFFu : 0u)
                  | (((bb >> (2 * w + 1)) & 1u) ? 0xFFFF0000u : 0u);
        lut[bb] = lv;
    }
    // adjacency bytes for this wave's 16 jt x 4 row-tiles (one-time)
    const unsigned char* ab = ADJP + g * 64 + jq * 16;
    u32x4 adjw0 = *(const u32x4*)(ab + (size_t)(i0 + l15) * 256);
    u32x4 adjw1 = *(const u32x4*)(ab + (size_t)(i0 + 16 + l15) * 256);
    u32x4 adjw2 = *(const u32x4*)(ab + (size_t)(i0 + 32 + l15) * 256);
    u32x4 adjw3 = *(const u32x4*)(ab + (size_t)(i0 + 48 + l15) * 256);
    _Float16 Ci0 = CIh[bc * NN + i0 + l15];
    _Float16 Ci1 = CIh[bc * NN + i0 + 16 + l15];
    _Float16 Ci2 = CIh[bc * NN + i0 + 32 + l15];
    _Float16 Ci3 = CIh[bc * NN + i0 + 48 + l15];
    __syncthreads();

    f32x4 acc[4][4];
    #pragma unroll
    for (int a = 0; a < 4; a++)
        #pragma unroll
        for (int nb = 0; nb < 4; nb++)
            acc[a][nb] = (f32x4){0.f, 0.f, 0.f, 0.f};
    f32x4 accz[4];
    #pragma unroll
    for (int a = 0; a < 4; a++) accz[a] = (f32x4){0.f, 0.f, 0.f, 0.f};
    half8 onesh;
    #pragma unroll
    for (int e = 0; e < 8; e++) onesh[e] = (_Float16)1.0f;

    const u32x4* xPbc = (const u32x4*)xP + (size_t)bc * 16384;

    // named pipeline registers for B fragments
    u32x4 A_x0, A_x1, A_x2, A_x3, B_x0, B_x1, B_x2, B_x3;

#define LOADX(P, J) do {                                                      \
        const u32x4* xw_ = xPbc + (((size_t)(jq * 16 + (J))) << 8) + lane;    \
        P##x0 = xw_[0]; P##x1 = xw_[64]; P##x2 = xw_[128]; P##x3 = xw_[192];  \
    } while (0)

#define GEN(AF, ADJW, CI) do {                                                \
        uint32_t b_ = (ADJW[(J_) >> 2] >> (((J_) & 3) * 8)) & 0xffu;          \
        u32x4 mm_ = lut[b_];                                                  \
        half8 mx_ = __builtin_elementwise_max(uu_, vv_ * (CI));               \
        AF = __builtin_bit_cast(half8, __builtin_bit_cast(u32x4, mx_) & mm_); \
    } while (0)

#define COMP(P, J) do {                                                       \
        const int J_ = (J);                                                   \
        const int jo_ = (jq * 16 + J_) * 32 + 8 * g;                          \
        half8 uu_ = *(const half8*)&su[jo_];                                  \
        half8 vv_ = *(const half8*)&sv[jo_];                                  \
        half8 af0_, af1_, af2_, af3_;                                         \
        GEN(af0_, adjw0, Ci0); GEN(af1_, adjw1, Ci1);                         \
        GEN(af2_, adjw2, Ci2); GEN(af3_, adjw3, Ci3);                         \
        half8 b0_ = __builtin_bit_cast(half8, P##x0);                         \
        half8 b1_ = __builtin_bit_cast(half8, P##x1);                         \
        half8 b2_ = __builtin_bit_cast(half8, P##x2);                         \
        half8 b3_ = __builtin_bit_cast(half8, P##x3);                         \
        __builtin_amdgcn_s_setprio(1);                                        \
        acc[0][0] = __builtin_amdgcn_mfma_f32_16x16x32_f16(af0_, b0_, acc[0][0], 0, 0, 0); \
        acc[0][1] = __builtin_amdgcn_mfma_f32_16x16x32_f16(af0_, b1_, acc[0][1], 0, 0, 0); \
        acc[0][2] = __builtin_amdgcn_mfma_f32_16x16x32_f16(af0_, b2_, acc[0][2], 0, 0, 0); \
        acc[0][3] = __builtin_amdgcn_mfma_f32_16x16x32_f16(af0_, b3_, acc[0][3], 0, 0, 0); \
        accz[0]   = __builtin_amdgcn_mfma_f32_16x16x32_f16(af0_, onesh, accz[0], 0, 0, 0); \
        acc[1][0] = __builtin_amdgcn_mfma_f32_16x16x32_f16(af1_, b0_, acc[1][0], 0, 0, 0); \
        acc[1][1] = __builtin_amdgcn_mfma_f32_16x16x32_f16(af1_, b1_, acc[1][1], 0, 0, 0); \
        acc[1][2] = __builtin_amdgcn_mfma_f32_16x16x32_f16(af1_, b2_, acc[1][2], 0, 0, 0); \
        acc[1][3] = __builtin_amdgcn_mfma_f32_16x16x32_f16(af1_, b3_, acc[1][3], 0, 0, 0); \
        accz[1]   = __builtin_amdgcn_mfma_f32_16x16x32_f16(af1_, onesh, accz[1], 0, 0, 0); \
        acc[2][0] = __builtin_amdgcn_mfma_f32_16x16x32_f16(af2_, b0_, acc[2][0], 0, 0, 0); \
        acc[2][1] = __builtin_amdgcn_mfma_f32_16x16x32_f16(af2_, b1_, acc[2][1], 0, 0, 0); \
        acc[2][2] = __builtin_amdgcn_mfma_f32_16x16x32_f16(af2_, b2_, acc[2][2], 0, 0, 0); \
        acc[2][3] = __builtin_amdgcn_mfma_f32_16x16x32_f16(af2_, b3_, acc[2][3], 0, 0, 0); \
        accz[2]   = __builtin_amdgcn_mfma_f32_16x16x32_f16(af2_, onesh, accz[2], 0, 0, 0); \
        acc[3][0] = __builtin_amdgcn_mfma_f32_16x16x32_f16(af3_, b0_, acc[3][0], 0, 0, 0); \
        acc[3][1] = __builtin_amdgcn_mfma_f32_16x16x32_f16(af3_, b1_, acc[3][1], 0, 0, 0); \
        acc[3][2] = __builtin_amdgcn_mfma_f32_16x16x32_f16(af3_, b2_, acc[3][2], 0, 0, 0); \
        acc[3][3] = __builtin_amdgcn_mfma_f32_16x16x32_f16(af3_, b3_, acc[3][3], 0, 0, 0); \
        accz[3]   = __builtin_amdgcn_mfma_f32_16x16x32_f16(af3_, onesh, accz[3], 0, 0, 0); \
        __builtin_amdgcn_s_setprio(0);                                        \
    } while (0)

    LOADX(A_, 0);
    LOADX(B_, 1);  COMP(A_, 0);
    LOADX(A_, 2);  COMP(B_, 1);
    LOADX(B_, 3);  COMP(A_, 2);
    LOADX(A_, 4);  COMP(B_, 3);
    LOADX(B_, 5);  COMP(A_, 4);
    LOADX(A_, 6);  COMP(B_, 5);
    LOADX(B_, 7);  COMP(A_, 6);
    LOADX(A_, 8);  COMP(B_, 7);
    LOADX(B_, 9);  COMP(A_, 8);
    LOADX(A_, 10); COMP(B_, 9);
    LOADX(B_, 11); COMP(A_, 10);
    LOADX(A_, 12); COMP(B_, 11);
    LOADX(B_, 13); COMP(A_, 12);
    LOADX(A_, 14); COMP(B_, 13);
    LOADX(B_, 15); COMP(A_, 14);
    COMP(B_, 15);
#undef LOADX
#undef GEN
#undef COMP

    // ---- epilogue: 4 passes (one per a-tile), 18 KB LDS ----
    float* outp = out + ((size_t)bc * NN + i0) * FF;
    #pragma unroll
    for (int a = 0; a < 4; a++) {
        #pragma unroll
        for (int nb = 0; nb < 4; nb++)
            #pragma unroll
            for (int r = 0; r < 4; r++)
                part[jq][4 * g + r][nb * 16 + l15] = acc[a][nb][r];
        if (l15 == 0) {
            #pragma unroll
            for (int r = 0; r < 4; r++)
                zp[jq][4 * g + r] = accz[a][r];
        }
        __syncthreads();
        #pragma unroll
        for (int rr = 0; rr < 4; rr++) {
            int row = jq * 4 + rr;
            float s = part[0][row][lane] + part[1][row][lane]
                    + part[2][row][lane] + part[3][row][lane];
            float z = zp[0][row] + zp[1][row] + zp[2][row] + zp[3][row];
            outp[(size_t)(16 * a + row) * FF + lane] = s / z;
        }
        __syncthreads();
    }
}

extern "C" void kernel_launch(void* const* d_in, const int* in_sizes, int n_in,
                              void* d_out, int out_size, void* d_ws, size_t ws_size,
                              hipStream_t stream) {
    const float* x  = (const float*)d_in[0];
    const int* adj  = (const int*)d_in[1];
    const float* a1 = (const float*)d_in[2];
    const float* a2 = (const float*)d_in[3];
    float* out = (float*)d_out;

    char* ws = (char*)d_ws;
    _Float16* xP  = (_Float16*)ws;
    _Float16* Uh  = (_Float16*)(ws + 4194304);
    _Float16* Vh  = (_Float16*)(ws + 4259840);
    _Float16* CIh = (_Float16*)(ws + 4325376);
    unsigned char* ADJP = (unsigned char*)(ws + 4390912);

    k_prep<<<512, 256, 0, stream>>>(x, adj, a1, a2, xP, Uh, Vh, CIh, ADJP);
    k_main<<<512, 256, 0, stream>>>(xP, Uh, Vh, CIh, ADJP, out);
}